// Round 19
// baseline (57.398 us; speedup 1.0000x reference)
//
#include <hip/hip_runtime.h>
#include <math.h>

#define W_ 128
#define H_ 96
#define C_ 128
#define HW_ (H_ * W_)          // 12288
#define K_ 81
#define FLOW_ELEMS (2 * 2 * H_ * W_)   // 49152
#define TSTR 66                // u32 stride per col (R16-verified layout)

typedef __fp16 f16x8 __attribute__((ext_vector_type(8)));
typedef float  f32x4 __attribute__((ext_vector_type(4)));

__device__ __forceinline__ unsigned pack_pair(float a, float b) {
    return __builtin_bit_cast(unsigned, __builtin_amdgcn_cvt_pkrtz(a, b));
}

// Round 19: K-SPLIT tiling to fix wave starvation (R15: Occupancy ~11%).
// Block = 256 thr (4 waves) per 16-px tile (b, y0, xq); wave wid owns the
// 32-channel quarter kk = wid. Per dy: stage 32 cols x 64 ch-pairs (f16) to
// LDS, each wave does 2 mfma_f32_16x16x32_f16 (its kk only), band dx in [0,8]
// merged across waves via LDS atomicAdd into corr_lds[16][85] (pre-zeroed).
// 3-set 2-deep pipeline + 2 barriers/dy = R18-verified schedule.
// Grid = 1536 blocks (8 XCD x 192); consecutive L share f1 halo rows.
__global__ __launch_bounds__(256) void fused_kernel(const float* __restrict__ f0,
                                                    const float* __restrict__ f1,
                                                    float* __restrict__ out) {
    __shared__ unsigned tile[32 * TSTR];      // 8448 B: [col][cp]
    __shared__ float corr_lds[16][85];        // 5440 B
    __shared__ float mbuf[16], ibuf[16];
    __shared__ float pmax[16][17], psum[16][17], pfxb[16][17], pfyb[16][17];

    const int t = threadIdx.x;
    const int wid = t >> 6, l = t & 63;       // wid == kk quarter
    const int L = (blockIdx.x & 7) * 192 + (blockIdx.x >> 3);   // 1536 = 8*192
    const int b = L / 768;
    const int rem = L - b * 768;
    const int y0 = rem >> 3;
    const int xq = rem & 7;
    const int px0 = xq * 16;

    // ---- staging slots: 2 per thread; slot s = i*256+t: cp = s>>3, q = s&7 ----
    // quad q covers cols 4q..4q+3 <-> sample x0 = px0 + 4q - 4 (zeros if OOB)
    int g_off[2], lds_w[2];
    bool g_ok[2];
#pragma unroll
    for (int i = 0; i < 2; ++i) {
        const int s = i * 256 + t;
        const int cp = s >> 3;
        const int q = s & 7;
        const int x0 = px0 + 4 * q - 4;
        g_ok[i] = (x0 >= 0) && (x0 <= 124);
        g_off[i] = 2 * cp * HW_ + (g_ok[i] ? x0 : 0);
        lds_w[i] = (4 * q) * TSTR + cp;
    }
    const float* f1base = f1 + (size_t)b * C_ * HW_;

    // ---- A-frag, single kk = wid (R14-verified layout): row=l&15, k=(l>>4)*8+j ----
    f16x8 a;
    {
        const float* f0p = f0 + (size_t)b * C_ * HW_ + (size_t)y0 * W_ + px0 + (l & 15);
#pragma unroll
        for (int j = 0; j < 8; ++j)
            a[j] = (__fp16)f0p[(size_t)(wid * 32 + (l >> 4) * 8 + j) * HW_];
    }

    // ---- pipeline helpers (R18-verified pattern, 2 slots instead of 5) ----
    auto LOADDY = [&](int dy, float4 (&va)[2], float4 (&vb)[2], bool& ok) {
        const int r = y0 + dy - 4;
        ok = (r >= 0) && (r < H_);
        const float* f1b = f1base + (size_t)(ok ? r : 0) * W_;
#pragma unroll
        for (int i = 0; i < 2; ++i) {
            float4 x = {0.f, 0.f, 0.f, 0.f}, y = {0.f, 0.f, 0.f, 0.f};
            if (ok && g_ok[i]) {
                x = *(const float4*)(f1b + g_off[i]);
                y = *(const float4*)(f1b + g_off[i] + HW_);
            }
            va[i] = x; vb[i] = y;
        }
    };
    auto WRITEDY = [&](const float4 (&va)[2], const float4 (&vb)[2]) {
#pragma unroll
        for (int i = 0; i < 2; ++i) {
            tile[lds_w[i]]            = pack_pair(va[i].x, vb[i].x);
            tile[lds_w[i] + TSTR]     = pack_pair(va[i].y, vb[i].y);
            tile[lds_w[i] + 2 * TSTR] = pack_pair(va[i].z, vb[i].z);
            tile[lds_w[i] + 3 * TSTR] = pack_pair(va[i].w, vb[i].w);
        }
    };
    auto COMPUTE = [&](int dy) {
        f32x4 accA = {0.f, 0.f, 0.f, 0.f}, accB = {0.f, 0.f, 0.f, 0.f};
        const int off = wid * 16 + (l >> 4) * 4;   // wave's kk cp-slice
        {
            const int col = l & 15;
            const uint2 lo = *(const uint2*)&tile[col * TSTR + off];
            const uint2 hi = *(const uint2*)&tile[col * TSTR + off + 2];
            const uint4 u = {lo.x, lo.y, hi.x, hi.y};
            accA = __builtin_amdgcn_mfma_f32_16x16x32_f16(
                a, __builtin_bit_cast(f16x8, u), accA, 0, 0, 0);
        }
        {
            const int col = 16 + (l & 15);
            const uint2 lo = *(const uint2*)&tile[col * TSTR + off];
            const uint2 hi = *(const uint2*)&tile[col * TSTR + off + 2];
            const uint4 u = {lo.x, lo.y, hi.x, hi.y};
            accB = __builtin_amdgcn_mfma_f32_16x16x32_f16(
                a, __builtin_bit_cast(f16x8, u), accB, 0, 0, 0);
        }
        // band extraction (R14-verified mapping) + cross-wave kk merge
#pragma unroll
        for (int h = 0; h < 2; ++h) {
            const f32x4 acc = h ? accB : accA;
#pragma unroll
            for (int rg = 0; rg < 4; ++rg) {
                const int i2 = (l >> 4) * 4 + rg;
                const int j2 = h * 16 + (l & 15);
                const int dxw = j2 - i2;
                if (dxw >= 0 && dxw <= 8)
                    atomicAdd(&corr_lds[i2][dy * 9 + dxw], acc[rg]);
            }
        }
    };

    float4 vaA[2], vbA[2], vaB[2], vbB[2], vaC[2], vbC[2];
    bool okA, okB, okC;

    LOADDY(0, vaA, vbA, okA);
    LOADDY(1, vaB, vbB, okB);
    for (int i = t; i < 16 * 85; i += 256) (&corr_lds[0][0])[i] = 0.f;
    __syncthreads();                      // corr zero visible

    // ---- fully-unrolled dy loop, 3-set rotation (R18-verified schedule) ----
    if (okA) WRITEDY(vaA, vbA); __syncthreads();
    LOADDY(2, vaC, vbC, okC);
    if (okA) COMPUTE(0); __syncthreads();

    if (okB) WRITEDY(vaB, vbB); __syncthreads();
    LOADDY(3, vaA, vbA, okA);
    if (okB) COMPUTE(1); __syncthreads();

    if (okC) WRITEDY(vaC, vbC); __syncthreads();
    LOADDY(4, vaB, vbB, okB);
    if (okC) COMPUTE(2); __syncthreads();

    if (okA) WRITEDY(vaA, vbA); __syncthreads();
    LOADDY(5, vaC, vbC, okC);
    if (okA) COMPUTE(3); __syncthreads();

    if (okB) WRITEDY(vaB, vbB); __syncthreads();
    LOADDY(6, vaA, vbA, okA);
    if (okB) COMPUTE(4); __syncthreads();

    if (okC) WRITEDY(vaC, vbC); __syncthreads();
    LOADDY(7, vaB, vbB, okB);
    if (okC) COMPUTE(5); __syncthreads();

    if (okA) WRITEDY(vaA, vbA); __syncthreads();
    LOADDY(8, vaC, vbC, okC);
    if (okA) COMPUTE(6); __syncthreads();

    if (okB) WRITEDY(vaB, vbB); __syncthreads();
    if (okB) COMPUTE(7); __syncthreads();

    if (okC) WRITEDY(vaC, vbC); __syncthreads();
    if (okC) COMPUTE(8); __syncthreads();

    const float scale = 0.08838834764831845f;     // 1/sqrt(128)

    // ---- pass 1 (16-way parallel): px = t&15, part = t>>4, k = part + 16j ----
    {
        const int px = t & 15;
        const int part = t >> 4;
        float pm = -1e30f;
        for (int k = part; k < K_; k += 16)
            pm = fmaxf(pm, corr_lds[px][k] * scale);
        pmax[part][px] = pm;
        __syncthreads();
        float m = -1e30f;
#pragma unroll
        for (int p = 0; p < 16; ++p) m = fmaxf(m, pmax[p][px]);
        if (part == 0) mbuf[px] = m;
        float ps = 0.f, pfx = 0.f, pfy = 0.f;
        for (int k = part; k < K_; k += 16) {
            const float e = __expf(corr_lds[px][k] * scale - m);
            ps += e;
            pfx += e * (float)(k % 9 - 4);
            pfy += e * (float)(k / 9 - 4);
        }
        psum[part][px] = ps; pfxb[part][px] = pfx; pfyb[part][px] = pfy;
        __syncthreads();
        if (t < 16) {
            float s = 0.f, fx = 0.f, fy = 0.f;
#pragma unroll
            for (int p = 0; p < 16; ++p) {
                s += psum[p][t]; fx += pfxb[p][t]; fy += pfyb[p][t];
            }
            const float inv = 1.f / s;
            ibuf[t] = inv;
            const int x = px0 + t;
            out[((size_t)(b * 2 + 0) * H_ + y0) * W_ + x] = fx * inv;
            out[((size_t)(b * 2 + 1) * H_ + y0) * W_ + x] = fy * inv;
        }
    }
    __syncthreads();

    // ---- pass 2: coalesced match_prob writeout (16 px x 81) ----
    float* mp = out + FLOW_ELEMS + ((size_t)b * HW_ + (size_t)y0 * W_ + px0) * K_;
    for (int f = t; f < 16 * K_; f += 256) {
        const int px = f / K_;
        const int k = f - px * K_;
        mp[f] = __expf(corr_lds[px][k] * scale - mbuf[px]) * ibuf[px];
    }
}

extern "C" void kernel_launch(void* const* d_in, const int* in_sizes, int n_in,
                              void* d_out, int out_size, void* d_ws, size_t ws_size,
                              hipStream_t stream) {
    (void)in_sizes; (void)n_in; (void)out_size; (void)d_ws; (void)ws_size;
    const float* f0 = (const float*)d_in[0];
    const float* f1 = (const float*)d_in[1];
    float* out = (float*)d_out;

    fused_kernel<<<1536, 256, 0, stream>>>(f0, f1, out);
}

// Round 20
// 36.388 us; speedup vs baseline: 1.5774x; 1.5774x over previous
//
#include <hip/hip_runtime.h>
#include <math.h>

#define W_ 128
#define H_ 96
#define C_ 128
#define HW_ (H_ * W_)          // 12288
#define K_ 81
#define FLOW_ELEMS (2 * 2 * H_ * W_)   // 49152

typedef __fp16 f16x8 __attribute__((ext_vector_type(8)));
typedef float  f32x4 __attribute__((ext_vector_type(4)));

__device__ __forceinline__ unsigned pack_pair(float a, float b) {
    return __builtin_bit_cast(unsigned, __builtin_amdgcn_cvt_pkrtz(a, b));
}

// Round 20: dy-split MFMA, barrier-free corr phase, max TLP.
// Block = 576 thr (9 waves) per (b, y0, xq) 16-px tile. Wave wid owns dy=wid
// EXCLUSIVELY: full-C banded product for halo row r = y0+wid-4, writing the
// disjoint k-slice [wid*9, wid*9+9) of corr_lds (R5-verified decomposition,
// R14-verified MFMA fragment + band-extract math). B-frags direct from raw
// f32 f1 (guarded dword loads + pkrtz; OOB -> exact zeros). No repack, no
// staging LDS, no atomics, NO barriers until softmax. 13824 waves (~4.5/SIMD).
// Grid = 1536 (8 XCD x 192).
__global__ __launch_bounds__(576, 5) void fused_kernel(const float* __restrict__ f0,
                                                       const float* __restrict__ f1,
                                                       float* __restrict__ out) {
    __shared__ float corr_lds[16][85];
    __shared__ float pmax[36][17], psum[36][17], pfxb[36][17], pfyb[36][17];
    __shared__ float mbuf[16], ibuf[16];

    const int t = threadIdx.x;
    const int wid = t >> 6;              // wave id == dy, 0..8
    const int l = t & 63;
    const int L = (blockIdx.x & 7) * 192 + (blockIdx.x >> 3);   // 1536 = 8*192
    const int xq = L & 7;
    const int y0 = (L >> 3) % H_;
    const int b  = L / 768;
    const int px0 = xq * 16;
    const int r  = y0 + wid - 4;         // this wave's halo row
    const bool rok = (r >= 0) && (r < H_);

    // each wave zeros its OWN k-slice (16 px x 9 k) -- no cross-wave interaction
    for (int i = l; i < 16 * 9; i += 64)
        corr_lds[i / 9][wid * 9 + (i % 9)] = 0.f;

    if (rok) {
        // ---- A-frags (R14-verified): row = l&15, k = kk*32 + (l>>4)*8 + j ----
        f16x8 a[4];
        {
            const float* f0p = f0 + (size_t)b * C_ * HW_ + (size_t)y0 * W_ + px0 + (l & 15);
#pragma unroll
            for (int kk = 0; kk < 4; ++kk) {
                f16x8 av;
#pragma unroll
                for (int j = 0; j < 8; ++j)
                    av[j] = (__fp16)f0p[(size_t)(kk * 32 + (l >> 4) * 8 + j) * HW_];
                a[kk] = av;
            }
        }

        // ---- B-frags direct from f32 f1; two 16-col tiles; band math = R14 ----
        // tile h: sample col x = px0 - 4 + h*16 + (l&15); zeros outside [0,127]
        const int xA = px0 - 4 + (l & 15);
        const int xB = xA + 16;
        const bool bokA = (xA >= 0) && (xA < W_);
        const bool bokB = (xB >= 0) && (xB < W_);
        const float* f1b = f1 + (size_t)b * C_ * HW_ + (size_t)r * W_;
        const int cb = (l >> 4) * 8;

        f32x4 accA = {0.f, 0.f, 0.f, 0.f}, accB = {0.f, 0.f, 0.f, 0.f};
#pragma unroll
        for (int kk = 0; kk < 4; ++kk) {
            float dA[8], dB[8];
#pragma unroll
            for (int j = 0; j < 8; ++j) {
                const size_t co = (size_t)(kk * 32 + cb + j) * HW_;
                dA[j] = bokA ? f1b[co + xA] : 0.f;
                dB[j] = bokB ? f1b[co + xB] : 0.f;
            }
            const uint4 uA = {pack_pair(dA[0], dA[1]), pack_pair(dA[2], dA[3]),
                              pack_pair(dA[4], dA[5]), pack_pair(dA[6], dA[7])};
            accA = __builtin_amdgcn_mfma_f32_16x16x32_f16(
                a[kk], __builtin_bit_cast(f16x8, uA), accA, 0, 0, 0);
            const uint4 uB = {pack_pair(dB[0], dB[1]), pack_pair(dB[2], dB[3]),
                              pack_pair(dB[4], dB[5]), pack_pair(dB[6], dB[7])};
            accB = __builtin_amdgcn_mfma_f32_16x16x32_f16(
                a[kk], __builtin_bit_cast(f16x8, uB), accB, 0, 0, 0);
        }

        // ---- band extraction (R14-verified): C col=l&15 (j2), row=(l>>4)*4+rg ----
#pragma unroll
        for (int h = 0; h < 2; ++h) {
            const f32x4 acc = h ? accB : accA;
#pragma unroll
            for (int rg = 0; rg < 4; ++rg) {
                const int i2 = (l >> 4) * 4 + rg;
                const int j2 = h * 16 + (l & 15);
                const int dxw = j2 - i2;
                if (dxw >= 0 && dxw <= 8)
                    corr_lds[i2][wid * 9 + dxw] = acc[rg];
            }
        }
    }
    __syncthreads();                     // corr complete (first barrier)

    const float scale = 0.08838834764831845f;     // 1/sqrt(128)

    // ---- softmax pass 1, 36-way parallel: px = t&15, part = t>>4 ----
    {
        const int px = t & 15;
        const int part = t >> 4;         // 0..35
        float pm = -1e30f;
        for (int k = part; k < K_; k += 36)
            pm = fmaxf(pm, corr_lds[px][k] * scale);
        pmax[part][px] = pm;
        __syncthreads();
        float m = -1e30f;
#pragma unroll
        for (int p = 0; p < 36; ++p) m = fmaxf(m, pmax[p][px]);
        float ps = 0.f, pfx = 0.f, pfy = 0.f;
        for (int k = part; k < K_; k += 36) {
            const float e = __expf(corr_lds[px][k] * scale - m);
            ps += e;
            pfx += e * (float)(k % 9 - 4);
            pfy += e * (float)(k / 9 - 4);
        }
        psum[part][px] = ps; pfxb[part][px] = pfx; pfyb[part][px] = pfy;
        if (part == 0) mbuf[px] = m;
        __syncthreads();
        if (t < 16) {
            float s = 0.f, fx = 0.f, fy = 0.f;
#pragma unroll
            for (int p = 0; p < 36; ++p) {
                s += psum[p][t]; fx += pfxb[p][t]; fy += pfyb[p][t];
            }
            const float inv = 1.f / s;
            ibuf[t] = inv;
            const int x = px0 + t;
            out[((size_t)(b * 2 + 0) * H_ + y0) * W_ + x] = fx * inv;
            out[((size_t)(b * 2 + 1) * H_ + y0) * W_ + x] = fy * inv;
        }
    }
    __syncthreads();

    // ---- pass 2: coalesced match_prob writeout (16 px x 81) ----
    float* mp = out + FLOW_ELEMS + ((size_t)b * HW_ + (size_t)y0 * W_ + px0) * K_;
    for (int f = t; f < 16 * K_; f += 576) {
        const int px = f / K_;
        const int k = f - px * K_;
        mp[f] = __expf(corr_lds[px][k] * scale - mbuf[px]) * ibuf[px];
    }
}

extern "C" void kernel_launch(void* const* d_in, const int* in_sizes, int n_in,
                              void* d_out, int out_size, void* d_ws, size_t ws_size,
                              hipStream_t stream) {
    (void)in_sizes; (void)n_in; (void)out_size; (void)d_ws; (void)ws_size;
    const float* f0 = (const float*)d_in[0];
    const float* f1 = (const float*)d_in[1];
    float* out = (float*)d_out;

    fused_kernel<<<1536, 576, 0, stream>>>(f0, f1, out);
}

// Round 21
// 27.731 us; speedup vs baseline: 2.0699x; 1.3122x over previous
//
#include <hip/hip_runtime.h>
#include <math.h>

#define W_ 128
#define H_ 96
#define C_ 128
#define HW_ (H_ * W_)          // 12288
#define K_ 81
#define FLOW_ELEMS (2 * 2 * H_ * W_)   // 49152
#define TCOLS 80               // staged xp cols per block (wave tiles need <= 79)
#define TSTR 66                // u32 stride per col (R16-verified layout)

typedef __fp16 f16x8 __attribute__((ext_vector_type(8)));
typedef float  f32x4 __attribute__((ext_vector_type(4)));

__device__ __forceinline__ unsigned pack_pair(float a, float b) {
    return __builtin_bit_cast(unsigned, __builtin_amdgcn_cvt_pkrtz(a, b));
}

// Round 21: R18 (champion, verified) with dy rows PAIRED per phase:
// 5 phases instead of 9 -> half the vmcnt-drain + barrier events, 2x MFMA
// latency cover per phase. Two LDS tiles (tile2[0/1]) hold the pair; two
// named register pair-sets rotate statically (rule #20). Staging map, A-frag,
// COMPUTE body, band extract, parallel softmax = R18 byte-identical.
// Block = 256 thr (4 waves) per (b, y0, xh) = 64 px. Grid = 384 (8 XCD x 48).
__global__ __launch_bounds__(256) void fused_kernel(const float* __restrict__ f0,
                                                    const float* __restrict__ f1,
                                                    float* __restrict__ out) {
    __shared__ unsigned tile2[2][TCOLS * TSTR];   // [row-of-pair][col][cp]
    __shared__ float corr_lds[64][85];
    __shared__ float mbuf[64], ibuf[64];
    __shared__ float pmax[4][68], psum[4][68], pfxb[4][68], pfyb[4][68];

    const int t = threadIdx.x;
    const int wid = t >> 6, l = t & 63;
    const int L = (blockIdx.x & 7) * 48 + (blockIdx.x >> 3);   // 384 = 8*48
    const int xh = L & 1;
    const int y0 = (L >> 1) % H_;
    const int b  = L / (2 * H_);
    const int px0 = xh * 64 + wid * 16;

    // ---- per-slot staging constants (R18-verified) ----
    int g_off[5], lds_w[5];
    bool g_ok[5];
#pragma unroll
    for (int i = 0; i < 5; ++i) {
        const int s = i * 256 + t;
        const int cp = s / 20;
        const int q = s - cp * 20;
        const int x0 = xh * 64 + 4 * q - 4;
        g_ok[i] = (x0 >= 0) && (x0 <= 124);
        g_off[i] = 2 * cp * HW_ + (g_ok[i] ? x0 : 0);
        lds_w[i] = (4 * q) * TSTR + cp;
    }
    const float* f1base = f1 + (size_t)b * C_ * HW_;

    // ---- A-frags (R14-verified): row=l&15, k=(l>>4)*8+j ----
    f16x8 a[4];
    {
        const float* f0p = f0 + (size_t)b * C_ * HW_ + (size_t)y0 * W_ + px0 + (l & 15);
#pragma unroll
        for (int kk = 0; kk < 4; ++kk) {
            f16x8 av;
#pragma unroll
            for (int j = 0; j < 8; ++j)
                av[j] = (__fp16)f0p[(size_t)(kk * 32 + (l >> 4) * 8 + j) * HW_];
            a[kk] = av;
        }
    }

    // ---- pair helpers: rows r0 = y0+2p-4, r1 = r0+1 (dy = 2p, 2p+1) ----
    auto LOADPAIR = [&](int p, float4 (&va)[5], float4 (&vb)[5],
                        float4 (&wa)[5], float4 (&wb)[5], bool& ok0, bool& ok1) {
        const int r0 = y0 + 2 * p - 4;
        const int r1 = r0 + 1;
        ok0 = (r0 >= 0) && (r0 < H_);
        ok1 = (2 * p + 1 <= 8) && (r1 >= 0) && (r1 < H_);
        const float* fb0 = f1base + (size_t)(ok0 ? r0 : 0) * W_;
        const float* fb1 = f1base + (size_t)(ok1 ? r1 : 0) * W_;
#pragma unroll
        for (int i = 0; i < 5; ++i) {
            float4 x0v = {0.f, 0.f, 0.f, 0.f}, y0v = {0.f, 0.f, 0.f, 0.f};
            float4 x1v = {0.f, 0.f, 0.f, 0.f}, y1v = {0.f, 0.f, 0.f, 0.f};
            if (ok0 && g_ok[i]) {
                x0v = *(const float4*)(fb0 + g_off[i]);
                y0v = *(const float4*)(fb0 + g_off[i] + HW_);
            }
            if (ok1 && g_ok[i]) {
                x1v = *(const float4*)(fb1 + g_off[i]);
                y1v = *(const float4*)(fb1 + g_off[i] + HW_);
            }
            va[i] = x0v; vb[i] = y0v; wa[i] = x1v; wb[i] = y1v;
        }
    };
    auto WRITEROW = [&](int slot, const float4 (&va)[5], const float4 (&vb)[5]) {
        unsigned* tl = tile2[slot];
#pragma unroll
        for (int i = 0; i < 5; ++i) {
            tl[lds_w[i]]            = pack_pair(va[i].x, vb[i].x);
            tl[lds_w[i] + TSTR]     = pack_pair(va[i].y, vb[i].y);
            tl[lds_w[i] + 2 * TSTR] = pack_pair(va[i].z, vb[i].z);
            tl[lds_w[i] + 3 * TSTR] = pack_pair(va[i].w, vb[i].w);
        }
    };
    auto COMPUTE = [&](int dy) {      // R18 body; tile source = tile2[dy&1]
        const unsigned* tl = tile2[dy & 1];
        f32x4 accA = {0.f, 0.f, 0.f, 0.f}, accB = {0.f, 0.f, 0.f, 0.f};
#pragma unroll
        for (int kk = 0; kk < 4; ++kk) {
            const int off = kk * 16 + (l >> 4) * 4;
            {
                const int col = wid * 16 + (l & 15);
                const uint2 lo = *(const uint2*)&tl[col * TSTR + off];
                const uint2 hi = *(const uint2*)&tl[col * TSTR + off + 2];
                const uint4 u = {lo.x, lo.y, hi.x, hi.y};
                accA = __builtin_amdgcn_mfma_f32_16x16x32_f16(
                    a[kk], __builtin_bit_cast(f16x8, u), accA, 0, 0, 0);
            }
            {
                const int col = wid * 16 + 16 + (l & 15);
                const uint2 lo = *(const uint2*)&tl[col * TSTR + off];
                const uint2 hi = *(const uint2*)&tl[col * TSTR + off + 2];
                const uint4 u = {lo.x, lo.y, hi.x, hi.y};
                accB = __builtin_amdgcn_mfma_f32_16x16x32_f16(
                    a[kk], __builtin_bit_cast(f16x8, u), accB, 0, 0, 0);
            }
        }
#pragma unroll
        for (int h = 0; h < 2; ++h) {
            const f32x4 acc = h ? accB : accA;
#pragma unroll
            for (int rg = 0; rg < 4; ++rg) {
                const int i2 = (l >> 4) * 4 + rg;
                const int j2 = h * 16 + (l & 15);
                const int dxw = j2 - i2;
                if (dxw >= 0 && dxw <= 8)
                    corr_lds[wid * 16 + i2][dy * 9 + dxw] = acc[rg];
            }
        }
    };

    // two named pair-sets (static rotation: even phases use set0, odd set1)
    float4 vaA[5], vbA[5], waA[5], wbA[5];
    float4 vaB[5], vbB[5], waB[5], wbB[5];
    bool okA0, okA1, okB0, okB1;

    LOADPAIR(0, vaA, vbA, waA, wbA, okA0, okA1);
    LOADPAIR(1, vaB, vbB, waB, wbB, okB0, okB1);
    for (int i = t; i < 64 * 85; i += 256) (&corr_lds[0][0])[i] = 0.f;
    __syncthreads();

    // P0: pair0 (dy 0,1); load pair2 -> set0
    if (okA0) WRITEROW(0, vaA, vbA);
    if (okA1) WRITEROW(1, waA, wbA);
    __syncthreads();
    LOADPAIR(2, vaA, vbA, waA, wbA, okA0, okA1);
    {
        // NOTE: ok flags for the pair being computed were consumed via the
        // writes above; compute guarded by row validity of THIS phase's pair.
        const int r0 = y0 + 0 - 4, r1 = r0 + 1;
        if (r0 >= 0 && r0 < H_) COMPUTE(0);
        if (r1 >= 0 && r1 < H_) COMPUTE(1);
    }
    __syncthreads();

    // P1: pair1 (dy 2,3); load pair3 -> set1
    if (okB0) WRITEROW(0, vaB, vbB);
    if (okB1) WRITEROW(1, waB, wbB);
    __syncthreads();
    LOADPAIR(3, vaB, vbB, waB, wbB, okB0, okB1);
    {
        const int r0 = y0 + 2 - 4, r1 = r0 + 1;
        if (r0 >= 0 && r0 < H_) COMPUTE(2);
        if (r1 >= 0 && r1 < H_) COMPUTE(3);
    }
    __syncthreads();

    // P2: pair2 (dy 4,5); load pair4 -> set0
    if (okA0) WRITEROW(0, vaA, vbA);
    if (okA1) WRITEROW(1, waA, wbA);
    __syncthreads();
    LOADPAIR(4, vaA, vbA, waA, wbA, okA0, okA1);
    {
        const int r0 = y0 + 4 - 4, r1 = r0 + 1;
        COMPUTE(4);                        // dy=4 always valid (r0 = y0)
        if (r1 >= 0 && r1 < H_) COMPUTE(5);
    }
    __syncthreads();

    // P3: pair3 (dy 6,7)
    if (okB0) WRITEROW(0, vaB, vbB);
    if (okB1) WRITEROW(1, waB, wbB);
    __syncthreads();
    {
        const int r0 = y0 + 6 - 4, r1 = r0 + 1;
        if (r0 >= 0 && r0 < H_) COMPUTE(6);
        if (r1 >= 0 && r1 < H_) COMPUTE(7);
    }
    __syncthreads();

    // P4: pair4 (dy 8 only)
    if (okA0) WRITEROW(0, vaA, vbA);
    __syncthreads();
    {
        const int r0 = y0 + 8 - 4;
        if (r0 >= 0 && r0 < H_) COMPUTE(8);
    }
    __syncthreads();

    const float scale = 0.08838834764831845f;     // 1/sqrt(128)

    // ---- pass 1 (R18-verified parallel softmax): px = t&63, part = t>>6 ----
    {
        const int px = t & 63;
        const int part = t >> 6;
        float pm = -1e30f;
        for (int k = part; k < K_; k += 4)
            pm = fmaxf(pm, corr_lds[px][k] * scale);
        pmax[part][px] = pm;
        __syncthreads();
        const float m = fmaxf(fmaxf(pmax[0][px], pmax[1][px]),
                              fmaxf(pmax[2][px], pmax[3][px]));
        float ps = 0.f, pfx = 0.f, pfy = 0.f;
        for (int k = part; k < K_; k += 4) {
            const float e = __expf(corr_lds[px][k] * scale - m);
            ps += e;
            pfx += e * (float)(k % 9 - 4);
            pfy += e * (float)(k / 9 - 4);
        }
        psum[part][px] = ps; pfxb[part][px] = pfx; pfyb[part][px] = pfy;
        __syncthreads();
        if (t < 64) {
            const float s = psum[0][t] + psum[1][t] + psum[2][t] + psum[3][t];
            const float inv = 1.f / s;
            mbuf[t] = m;
            ibuf[t] = inv;
            const float fx = pfxb[0][t] + pfxb[1][t] + pfxb[2][t] + pfxb[3][t];
            const float fy = pfyb[0][t] + pfyb[1][t] + pfyb[2][t] + pfyb[3][t];
            const int x = xh * 64 + t;
            out[((size_t)(b * 2 + 0) * H_ + y0) * W_ + x] = fx * inv;
            out[((size_t)(b * 2 + 1) * H_ + y0) * W_ + x] = fy * inv;
        }
    }
    __syncthreads();

    // ---- pass 2: coalesced match_prob writeout (R14-verified) ----
    float* mp = out + FLOW_ELEMS + ((size_t)b * HW_ + (size_t)y0 * W_ + xh * 64) * K_;
    for (int f = t; f < 64 * K_; f += 256) {
        const int px = f / K_;
        const int k = f - px * K_;
        mp[f] = __expf(corr_lds[px][k] * scale - mbuf[px]) * ibuf[px];
    }
}

extern "C" void kernel_launch(void* const* d_in, const int* in_sizes, int n_in,
                              void* d_out, int out_size, void* d_ws, size_t ws_size,
                              hipStream_t stream) {
    (void)in_sizes; (void)n_in; (void)out_size; (void)d_ws; (void)ws_size;
    const float* f0 = (const float*)d_in[0];
    const float* f1 = (const float*)d_in[1];
    float* out = (float*)d_out;

    fused_kernel<<<384, 256, 0, stream>>>(f0, f1, out);
}

// Round 22
// 23.817 us; speedup vs baseline: 2.4100x; 1.1643x over previous
//
#include <hip/hip_runtime.h>
#include <math.h>

#define W_ 128
#define H_ 96
#define C_ 128
#define HW_ (H_ * W_)          // 12288
#define K_ 81
#define FLOW_ELEMS (2 * 2 * H_ * W_)   // 49152
#define TCOLS 48               // staged cols: samples px0-4 .. px0+43
#define TSTR 66                // u32 stride per col (R16/R18-verified layout)

typedef __fp16 f16x8 __attribute__((ext_vector_type(8)));
typedef float  f32x4 __attribute__((ext_vector_type(4)));

__device__ __forceinline__ unsigned pack_pair(float a, float b) {
    return __builtin_bit_cast(unsigned, __builtin_amdgcn_cvt_pkrtz(a, b));
}

// Round 22: balanced grid + y-strip halo reuse.
// Block = 384 thr (6 waves = 3 ry x 2 xt) per (b, y-strip of 3 rows, 32-px xq).
// Grid = 2*32*4 = 256 blocks = EXACTLY 1/CU (no 2nd block-round, no imbalance).
// 11 phases stage halo rows y0-4..y0+6 ONCE each (48 cols x 128 ch, f16 pairs);
// wave (ry,xt) computes dy = p - ry when in [0,8]: 8 MFMAs + band extract into
// its exclusive corr_lds[ry][xt*16..+15][*] slice. R18-verified per-phase
// mechanics (slot map, TSTR layout, COMPUTE body, 3-set 2-deep rotation).
// Scale folded into A-frags; softmax caches exp in corr_lds (pass2 = mul).
__global__ __launch_bounds__(384) void fused_kernel(const float* __restrict__ f0,
                                                    const float* __restrict__ f1,
                                                    float* __restrict__ out) {
    __shared__ unsigned tile[TCOLS * TSTR];          // 12672 B
    __shared__ float corr_lds[3][32][85];            // 32640 B
    __shared__ float pmax[4][96], psum[4][96], pfxb[4][96], pfyb[4][96];
    __shared__ float ibuf[96];

    const int t = threadIdx.x;
    const int wid = t >> 6, l = t & 63;
    const int ry = wid >> 1, xt = wid & 1;
    const int L = (blockIdx.x & 7) * 32 + (blockIdx.x >> 3);   // 256 = 8*32
    const int b = L >> 7;
    const int rem = L & 127;
    const int ys = rem >> 2, xq = rem & 3;
    const int y0 = ys * 3;               // rows y0, y0+1, y0+2
    const int px0 = xq * 32;
    const int pxw = px0 + xt * 16;       // wave's A-tile base pixel

    // ---- staging slots: 2/thread; s = i*384+t: cp = s/12, quad q = s%12 ----
    // quad q covers local cols 4q..4q+3 <-> samples x0 = px0 + 4q - 4 (+0..3)
    int g_off[2], lds_w[2];
    bool g_ok[2];
#pragma unroll
    for (int i = 0; i < 2; ++i) {
        const int s = i * 384 + t;
        const int cp = s / 12;
        const int q = s - cp * 12;
        const int x0 = px0 + 4 * q - 4;
        g_ok[i] = (x0 >= 0) && (x0 <= 124);
        g_off[i] = 2 * cp * HW_ + (g_ok[i] ? x0 : 0);
        lds_w[i] = (4 * q) * TSTR + cp;
    }
    const float* f1base = f1 + (size_t)b * C_ * HW_;

    // ---- A-frags (R14-verified layout), row y0+ry, SCALE FOLDED ----
    const float scale = 0.08838834764831845f;   // 1/sqrt(128)
    f16x8 a[4];
    {
        const float* f0p = f0 + (size_t)b * C_ * HW_ + (size_t)(y0 + ry) * W_
                              + pxw + (l & 15);
#pragma unroll
        for (int kk = 0; kk < 4; ++kk) {
            f16x8 av;
#pragma unroll
            for (int j = 0; j < 8; ++j)
                av[j] = (__fp16)(f0p[(size_t)(kk * 32 + (l >> 4) * 8 + j) * HW_] * scale);
            a[kk] = av;
        }
    }

    // ---- helpers (R18-verified patterns) ----
    auto LOADP = [&](int p, float4 (&va)[2], float4 (&vb)[2], bool& ok) {
        const int r = y0 - 4 + p;
        ok = (r >= 0) && (r < H_);
        const float* f1b = f1base + (size_t)(ok ? r : 0) * W_;
#pragma unroll
        for (int i = 0; i < 2; ++i) {
            float4 x = {0.f, 0.f, 0.f, 0.f}, y = {0.f, 0.f, 0.f, 0.f};
            if (ok && g_ok[i]) {
                x = *(const float4*)(f1b + g_off[i]);
                y = *(const float4*)(f1b + g_off[i] + HW_);
            }
            va[i] = x; vb[i] = y;
        }
    };
    auto WRITEP = [&](const float4 (&va)[2], const float4 (&vb)[2]) {
#pragma unroll
        for (int i = 0; i < 2; ++i) {
            tile[lds_w[i]]            = pack_pair(va[i].x, vb[i].x);
            tile[lds_w[i] + TSTR]     = pack_pair(va[i].y, vb[i].y);
            tile[lds_w[i] + 2 * TSTR] = pack_pair(va[i].z, vb[i].z);
            tile[lds_w[i] + 3 * TSTR] = pack_pair(va[i].w, vb[i].w);
        }
    };
    auto COMPUTE = [&](int dyi) {        // dyi = p - ry in [0,8]
        f32x4 accA = {0.f, 0.f, 0.f, 0.f}, accB = {0.f, 0.f, 0.f, 0.f};
#pragma unroll
        for (int kk = 0; kk < 4; ++kk) {
            const int off = kk * 16 + (l >> 4) * 4;
            {
                const int col = xt * 16 + (l & 15);
                const uint2 lo = *(const uint2*)&tile[col * TSTR + off];
                const uint2 hi = *(const uint2*)&tile[col * TSTR + off + 2];
                const uint4 u = {lo.x, lo.y, hi.x, hi.y};
                accA = __builtin_amdgcn_mfma_f32_16x16x32_f16(
                    a[kk], __builtin_bit_cast(f16x8, u), accA, 0, 0, 0);
            }
            {
                const int col = xt * 16 + 16 + (l & 15);
                const uint2 lo = *(const uint2*)&tile[col * TSTR + off];
                const uint2 hi = *(const uint2*)&tile[col * TSTR + off + 2];
                const uint4 u = {lo.x, lo.y, hi.x, hi.y};
                accB = __builtin_amdgcn_mfma_f32_16x16x32_f16(
                    a[kk], __builtin_bit_cast(f16x8, u), accB, 0, 0, 0);
            }
        }
        // band extract (R14-verified): i2 = C row, j2 = C col(+h*16); dx = j2-i2
#pragma unroll
        for (int h = 0; h < 2; ++h) {
            const f32x4 acc = h ? accB : accA;
#pragma unroll
            for (int rg = 0; rg < 4; ++rg) {
                const int i2 = (l >> 4) * 4 + rg;
                const int j2 = h * 16 + (l & 15);
                const int dxw = j2 - i2;
                if (dxw >= 0 && dxw <= 8)
                    corr_lds[ry][xt * 16 + i2][dyi * 9 + dxw] = acc[rg];
            }
        }
    };

    float4 vaA[2], vbA[2], vaB[2], vbB[2], vaC[2], vbC[2];
    bool okA, okB, okC;

    LOADP(0, vaA, vbA, okA);
    LOADP(1, vaB, vbB, okB);
    for (int i = t; i < 3 * 32 * 85; i += 384) (&corr_lds[0][0][0])[i] = 0.f;
    __syncthreads();

    // ---- 11 phases, sets A,B,C,A,B,C,A,B,C,A,B; load p+2 during p ----
#define PHASE(p, VA, VB, OK, LP, NVA, NVB, NOK)                              \
    do {                                                                     \
        if (OK) WRITEP(VA, VB);                                              \
        __syncthreads();                                                     \
        if (LP <= 10) LOADP(LP, NVA, NVB, NOK);                              \
        const int dyi = (p) - ry;                                            \
        if (OK && dyi >= 0 && dyi <= 8) COMPUTE(dyi);                        \
        __syncthreads();                                                     \
    } while (0)

    PHASE(0, vaA, vbA, okA, 2, vaC, vbC, okC);
    PHASE(1, vaB, vbB, okB, 3, vaA, vbA, okA);
    PHASE(2, vaC, vbC, okC, 4, vaB, vbB, okB);
    PHASE(3, vaA, vbA, okA, 5, vaC, vbC, okC);
    PHASE(4, vaB, vbB, okB, 6, vaA, vbA, okA);
    PHASE(5, vaC, vbC, okC, 7, vaB, vbB, okB);
    PHASE(6, vaA, vbA, okA, 8, vaC, vbC, okC);
    PHASE(7, vaB, vbB, okB, 9, vaA, vbA, okA);
    PHASE(8, vaC, vbC, okC, 10, vaB, vbB, okB);
    PHASE(9, vaA, vbA, okA, 11, vaC, vbC, okC);   // LP=11 > 10: no load
    PHASE(10, vaB, vbB, okB, 11, vaC, vbC, okC);
#undef PHASE

    // ---- softmax pass 1: pxi = t%96 (ry = pxi>>5, px = pxi&31), part = t/96 ----
    {
        const int pxi = t % 96;
        const int part = t / 96;
        const int sry = pxi >> 5, spx = pxi & 31;
        float pm = -1e30f;
        for (int k = part; k < K_; k += 4)
            pm = fmaxf(pm, corr_lds[sry][spx][k]);      // scale already folded
        pmax[part][pxi] = pm;
        __syncthreads();
        const float m = fmaxf(fmaxf(pmax[0][pxi], pmax[1][pxi]),
                              fmaxf(pmax[2][pxi], pmax[3][pxi]));
        float ps = 0.f, pfx = 0.f, pfy = 0.f;
        for (int k = part; k < K_; k += 4) {
            const float e = __expf(corr_lds[sry][spx][k] - m);
            corr_lds[sry][spx][k] = e;                  // cache exp for pass 2
            ps += e;
            pfx += e * (float)(k % 9 - 4);
            pfy += e * (float)(k / 9 - 4);
        }
        psum[part][pxi] = ps; pfxb[part][pxi] = pfx; pfyb[part][pxi] = pfy;
        __syncthreads();
        if (t < 96) {
            const float s = psum[0][t] + psum[1][t] + psum[2][t] + psum[3][t];
            const float inv = 1.f / s;
            ibuf[t] = inv;
            const float fx = pfxb[0][t] + pfxb[1][t] + pfxb[2][t] + pfxb[3][t];
            const float fy = pfyb[0][t] + pfyb[1][t] + pfyb[2][t] + pfyb[3][t];
            const int yy = y0 + (t >> 5);
            const int x = px0 + (t & 31);
            out[((size_t)(b * 2 + 0) * H_ + yy) * W_ + x] = fx * inv;
            out[((size_t)(b * 2 + 1) * H_ + yy) * W_ + x] = fy * inv;
        }
    }
    __syncthreads();

    // ---- pass 2: match_prob = cached exp * inv (coalesced) ----
    float* outp = out + FLOW_ELEMS;
    for (int f = t; f < 96 * K_; f += 384) {
        const int pxi = f / K_;
        const int k = f - pxi * K_;
        const int yy = y0 + (pxi >> 5);
        const int x = px0 + (pxi & 31);
        outp[((size_t)b * HW_ + (size_t)yy * W_ + x) * K_ + k] =
            corr_lds[pxi >> 5][pxi & 31][k] * ibuf[pxi];
    }
}

extern "C" void kernel_launch(void* const* d_in, const int* in_sizes, int n_in,
                              void* d_out, int out_size, void* d_ws, size_t ws_size,
                              hipStream_t stream) {
    (void)in_sizes; (void)n_in; (void)out_size; (void)d_ws; (void)ws_size;
    const float* f0 = (const float*)d_in[0];
    const float* f1 = (const float*)d_in[1];
    float* out = (float*)d_out;

    fused_kernel<<<256, 384, 0, stream>>>(f0, f1, out);
}

// Round 23
// 22.648 us; speedup vs baseline: 2.5344x; 1.0516x over previous
//
#include <hip/hip_runtime.h>
#include <math.h>

#define W_ 128
#define H_ 96
#define C_ 128
#define HW_ (H_ * W_)          // 12288
#define K_ 81
#define FLOW_ELEMS (2 * 2 * H_ * W_)   // 49152
#define TCOLS 32               // tile cols allocated; 24 staged (cols 24..31 unused:
                               // their outputs have dx>=9, always band-discarded)
#define TSTR 66                // u32 stride per col (R16/R18/R22-verified layout)

typedef __fp16 f16x8 __attribute__((ext_vector_type(8)));
typedef float  f32x4 __attribute__((ext_vector_type(4)));

__device__ __forceinline__ unsigned pack_pair(float a, float b) {
    return __builtin_bit_cast(unsigned, __builtin_amdgcn_cvt_pkrtz(a, b));
}

// Round 23: R22 (champion) at HALF block width -> 512 blocks = exactly
// 2 blocks/CU. Iso-everything (waves/CU, staged bytes, MFMA count, schedule);
// the only delta: two independent barrier domains per CU, so one block's
// compute hides the other's vmcnt/barrier stalls.
// Block = 192 thr (3 waves = rows y0..y0+2, one 16-px tile). 11 phases stage
// halo rows y0-4..y0+6 once each (24 cols x 128 ch f16 pairs, 2 slots/thread).
__global__ __launch_bounds__(192) void fused_kernel(const float* __restrict__ f0,
                                                    const float* __restrict__ f1,
                                                    float* __restrict__ out) {
    __shared__ unsigned tile[TCOLS * TSTR];          // 8448 B (cols 24..31 unwritten)
    __shared__ float corr_lds[3][16][85];            // 16320 B
    __shared__ float pmax[4][49], psum[4][49], pfxb[4][49], pfyb[4][49];
    __shared__ float ibuf[48];

    const int t = threadIdx.x;
    const int ry = t >> 6, l = t & 63;   // wave id == output row within strip
    const int L = (blockIdx.x & 7) * 64 + (blockIdx.x >> 3);   // 512 = 8*64
    const int b = L >> 8;
    const int rem = L & 255;
    const int ys = rem >> 3, xq = rem & 7;
    const int y0 = ys * 3;               // rows y0, y0+1, y0+2
    const int px0 = xq * 16;             // 16-px tile base

    // ---- staging slots: exactly 2/thread; s = i*192+t: cp = s/6, quad q = s%6 ----
    // quad q covers local cols 4q..4q+3 <-> samples x0 = px0 + 4q - 4 (+0..3)
    int g_off[2], lds_w[2];
    bool g_ok[2];
#pragma unroll
    for (int i = 0; i < 2; ++i) {
        const int s = i * 192 + t;
        const int cp = s / 6;
        const int q = s - cp * 6;
        const int x0 = px0 + 4 * q - 4;
        g_ok[i] = (x0 >= 0) && (x0 <= 124);
        g_off[i] = 2 * cp * HW_ + (g_ok[i] ? x0 : 0);
        lds_w[i] = (4 * q) * TSTR + cp;
    }
    const float* f1base = f1 + (size_t)b * C_ * HW_;

    // ---- A-frags (R14-verified layout), row y0+ry, scale folded ----
    const float scale = 0.08838834764831845f;   // 1/sqrt(128)
    f16x8 a[4];
    {
        const float* f0p = f0 + (size_t)b * C_ * HW_ + (size_t)(y0 + ry) * W_
                              + px0 + (l & 15);
#pragma unroll
        for (int kk = 0; kk < 4; ++kk) {
            f16x8 av;
#pragma unroll
            for (int j = 0; j < 8; ++j)
                av[j] = (__fp16)(f0p[(size_t)(kk * 32 + (l >> 4) * 8 + j) * HW_] * scale);
            a[kk] = av;
        }
    }

    // ---- helpers (R22-verified patterns) ----
    auto LOADP = [&](int p, float4 (&va)[2], float4 (&vb)[2], bool& ok) {
        const int r = y0 - 4 + p;
        ok = (r >= 0) && (r < H_);
        const float* f1b = f1base + (size_t)(ok ? r : 0) * W_;
#pragma unroll
        for (int i = 0; i < 2; ++i) {
            float4 x = {0.f, 0.f, 0.f, 0.f}, y = {0.f, 0.f, 0.f, 0.f};
            if (ok && g_ok[i]) {
                x = *(const float4*)(f1b + g_off[i]);
                y = *(const float4*)(f1b + g_off[i] + HW_);
            }
            va[i] = x; vb[i] = y;
        }
    };
    auto WRITEP = [&](const float4 (&va)[2], const float4 (&vb)[2]) {
#pragma unroll
        for (int i = 0; i < 2; ++i) {
            tile[lds_w[i]]            = pack_pair(va[i].x, vb[i].x);
            tile[lds_w[i] + TSTR]     = pack_pair(va[i].y, vb[i].y);
            tile[lds_w[i] + 2 * TSTR] = pack_pair(va[i].z, vb[i].z);
            tile[lds_w[i] + 3 * TSTR] = pack_pair(va[i].w, vb[i].w);
        }
    };
    auto COMPUTE = [&](int dyi) {        // dyi = p - ry in [0,8]
        f32x4 accA = {0.f, 0.f, 0.f, 0.f}, accB = {0.f, 0.f, 0.f, 0.f};
#pragma unroll
        for (int kk = 0; kk < 4; ++kk) {
            const int off = kk * 16 + (l >> 4) * 4;
            {
                const int col = l & 15;
                const uint2 lo = *(const uint2*)&tile[col * TSTR + off];
                const uint2 hi = *(const uint2*)&tile[col * TSTR + off + 2];
                const uint4 u = {lo.x, lo.y, hi.x, hi.y};
                accA = __builtin_amdgcn_mfma_f32_16x16x32_f16(
                    a[kk], __builtin_bit_cast(f16x8, u), accA, 0, 0, 0);
            }
            {
                const int col = 16 + (l & 15);   // cols 24..31: outputs discarded
                const uint2 lo = *(const uint2*)&tile[col * TSTR + off];
                const uint2 hi = *(const uint2*)&tile[col * TSTR + off + 2];
                const uint4 u = {lo.x, lo.y, hi.x, hi.y};
                accB = __builtin_amdgcn_mfma_f32_16x16x32_f16(
                    a[kk], __builtin_bit_cast(f16x8, u), accB, 0, 0, 0);
            }
        }
        // band extract (R14-verified): dx = j2 - i2 in [0,8]
#pragma unroll
        for (int h = 0; h < 2; ++h) {
            const f32x4 acc = h ? accB : accA;
#pragma unroll
            for (int rg = 0; rg < 4; ++rg) {
                const int i2 = (l >> 4) * 4 + rg;
                const int j2 = h * 16 + (l & 15);
                const int dxw = j2 - i2;
                if (dxw >= 0 && dxw <= 8)
                    corr_lds[ry][i2][dyi * 9 + dxw] = acc[rg];
            }
        }
    };

    float4 vaA[2], vbA[2], vaB[2], vbB[2], vaC[2], vbC[2];
    bool okA, okB, okC;

    LOADP(0, vaA, vbA, okA);
    LOADP(1, vaB, vbB, okB);
    for (int i = t; i < 3 * 16 * 85; i += 192) (&corr_lds[0][0][0])[i] = 0.f;
    __syncthreads();

    // ---- 11 phases, sets A,B,C rotation; load p+2 during p (R22-verified) ----
#define PHASE(p, VA, VB, OK, LP, NVA, NVB, NOK)                              \
    do {                                                                     \
        if (OK) WRITEP(VA, VB);                                              \
        __syncthreads();                                                     \
        if (LP <= 10) LOADP(LP, NVA, NVB, NOK);                              \
        const int dyi = (p) - ry;                                            \
        if (OK && dyi >= 0 && dyi <= 8) COMPUTE(dyi);                        \
        __syncthreads();                                                     \
    } while (0)

    PHASE(0, vaA, vbA, okA, 2, vaC, vbC, okC);
    PHASE(1, vaB, vbB, okB, 3, vaA, vbA, okA);
    PHASE(2, vaC, vbC, okC, 4, vaB, vbB, okB);
    PHASE(3, vaA, vbA, okA, 5, vaC, vbC, okC);
    PHASE(4, vaB, vbB, okB, 6, vaA, vbA, okA);
    PHASE(5, vaC, vbC, okC, 7, vaB, vbB, okB);
    PHASE(6, vaA, vbA, okA, 8, vaC, vbC, okC);
    PHASE(7, vaB, vbB, okB, 9, vaA, vbA, okA);
    PHASE(8, vaC, vbC, okC, 10, vaB, vbB, okB);
    PHASE(9, vaA, vbA, okA, 11, vaC, vbC, okC);   // LP=11 > 10: no load
    PHASE(10, vaB, vbB, okB, 11, vaC, vbC, okC);
#undef PHASE

    // ---- softmax pass 1: pxi = t%48 (sry = pxi>>4, spx = pxi&15), part = t/48 ----
    {
        const int pxi = t % 48;
        const int part = t / 48;
        const int sry = pxi >> 4, spx = pxi & 15;
        float pm = -1e30f;
        for (int k = part; k < K_; k += 4)
            pm = fmaxf(pm, corr_lds[sry][spx][k]);      // scale already folded
        pmax[part][pxi] = pm;
        __syncthreads();
        const float m = fmaxf(fmaxf(pmax[0][pxi], pmax[1][pxi]),
                              fmaxf(pmax[2][pxi], pmax[3][pxi]));
        float ps = 0.f, pfx = 0.f, pfy = 0.f;
        for (int k = part; k < K_; k += 4) {
            const float e = __expf(corr_lds[sry][spx][k] - m);
            corr_lds[sry][spx][k] = e;                  // cache exp for pass 2
            ps += e;
            pfx += e * (float)(k % 9 - 4);
            pfy += e * (float)(k / 9 - 4);
        }
        psum[part][pxi] = ps; pfxb[part][pxi] = pfx; pfyb[part][pxi] = pfy;
        __syncthreads();
        if (t < 48) {
            const float s = psum[0][t] + psum[1][t] + psum[2][t] + psum[3][t];
            const float inv = 1.f / s;
            ibuf[t] = inv;
            const float fx = pfxb[0][t] + pfxb[1][t] + pfxb[2][t] + pfxb[3][t];
            const float fy = pfyb[0][t] + pfyb[1][t] + pfyb[2][t] + pfyb[3][t];
            const int yy = y0 + (t >> 4);
            const int x = px0 + (t & 15);
            out[((size_t)(b * 2 + 0) * H_ + yy) * W_ + x] = fx * inv;
            out[((size_t)(b * 2 + 1) * H_ + yy) * W_ + x] = fy * inv;
        }
    }
    __syncthreads();

    // ---- pass 2: match_prob = cached exp * inv (coalesced) ----
    float* outp = out + FLOW_ELEMS;
    for (int f = t; f < 48 * K_; f += 192) {
        const int pxi = f / K_;
        const int k = f - pxi * K_;
        const int yy = y0 + (pxi >> 4);
        const int x = px0 + (pxi & 15);
        outp[((size_t)b * HW_ + (size_t)yy * W_ + x) * K_ + k] =
            corr_lds[pxi >> 4][pxi & 15][k] * ibuf[pxi];
    }
}

extern "C" void kernel_launch(void* const* d_in, const int* in_sizes, int n_in,
                              void* d_out, int out_size, void* d_ws, size_t ws_size,
                              hipStream_t stream) {
    (void)in_sizes; (void)n_in; (void)out_size; (void)d_ws; (void)ws_size;
    const float* f0 = (const float*)d_in[0];
    const float* f1 = (const float*)d_in[1];
    float* out = (float*)d_out;

    fused_kernel<<<512, 192, 0, stream>>>(f0, f1, out);
}